// Round 6
// baseline (1055.196 us; speedup 1.0000x reference)
//
#include <hip/hip_runtime.h>

typedef __bf16 bf16x8 __attribute__((ext_vector_type(8)));
typedef float  f32x4  __attribute__((ext_vector_type(4)));
typedef unsigned short us4 __attribute__((ext_vector_type(4)));

#define NF   100
#define NFT  112      // padded factor count (7*16)
#define NG   8000     // genes (= cols of G, rows of A)
#define NR   20000    // regions (= cols of R and A)
#define NC   8000     // cells (rows of G and R)

static __device__ __forceinline__ unsigned short f2bf_bits(float f) {
  unsigned u = __builtin_bit_cast(unsigned, f);
  u = (u + 0x7FFFu + ((u >> 16) & 1u)) >> 16;   // RNE
  return (unsigned short)u;
}
static __device__ __forceinline__ __bf16 f2bf(float f) {
  unsigned short h = f2bf_bits(f);
  return __builtin_bit_cast(__bf16, h);
}
static __device__ __forceinline__ float bf2f(unsigned short s) {
  unsigned u = ((unsigned)s) << 16;
  return __builtin_bit_cast(float, u);
}
static __device__ __forceinline__ bf16x8 cvt8(f32x4 v0, f32x4 v1) {
  bf16x8 r;
  r[0]=f2bf(v0[0]); r[1]=f2bf(v0[1]); r[2]=f2bf(v0[2]); r[3]=f2bf(v0[3]);
  r[4]=f2bf(v1[0]); r[5]=f2bf(v1[1]); r[6]=f2bf(v1[2]); r[7]=f2bf(v1[3]);
  return r;
}

// ============ pre-pass: softmaxes -> augmented operand panels + loss3 ============
// blocks [0,8000): C1 -> T1a[cell][112] (cols: T1=S1@Ag | 1.0 | b1 | 0)
//        [8000,16000): C2 -> T2a
//        [16000,24000): Cg -> SgT[112][8000] (rows: Sg^T | 1.0 | bg | 0)
//        [24000,44000): Cr -> SrT[112][20000] (rows: Sr^T | 1.0 | br | 0)
//        44000: loss3 pieces.
__global__ __launch_bounds__(64) void pre_kernel(
    const float* __restrict__ C1, const float* __restrict__ C2,
    const float* __restrict__ Cg, const float* __restrict__ Cr,
    const float* __restrict__ Ag, const float* __restrict__ Ar,
    const float* __restrict__ b1, const float* __restrict__ b2,
    const float* __restrict__ bg, const float* __restrict__ br,
    unsigned short* __restrict__ T1a, unsigned short* __restrict__ T2a,
    unsigned short* __restrict__ SgT, unsigned short* __restrict__ SrT,
    float* __restrict__ accv) {
  __shared__ float srow[NF];
  int b = blockIdx.x, t = threadIdx.x;
  if (b >= 44000) {            // loss3
    float d = 0.f, na = 0.f, nr = 0.f;
    for (int i = t; i < NF * NF; i += 64) {
      float a = Ag[i], r = Ar[i];
      d = fmaf(a, r, d); na = fmaf(a, a, na); nr = fmaf(r, r, nr);
    }
    #pragma unroll
    for (int off = 32; off > 0; off >>= 1) {
      d += __shfl_xor(d, off); na += __shfl_xor(na, off); nr += __shfl_xor(nr, off);
    }
    if (t == 0) { accv[2] = d; accv[3] = na; accv[4] = nr; }
    return;
  }
  const float* C; const float* W = nullptr; const float* bvec;
  unsigned short* outT = nullptr; unsigned short* outS = nullptr;
  int i, scols = 0;
  if (b < 8000)       { C = C1; W = Ag; bvec = b1; outT = T1a; i = b; }
  else if (b < 16000) { C = C2; W = Ar; bvec = b2; outT = T2a; i = b - 8000; }
  else if (b < 24000) { C = Cg; bvec = bg; outS = SgT; scols = NG; i = b - 16000; }
  else                { C = Cr; bvec = br; outS = SrT; scols = NR; i = b - 24000; }

  // softmax over 100: lane t holds elem t and (t<36) elem 64+t
  float v0 = C[i * NF + t];
  float v1 = (t < 36) ? C[i * NF + 64 + t] : -3.0e38f;
  float m = fmaxf(v0, v1);
  #pragma unroll
  for (int off = 32; off > 0; off >>= 1) m = fmaxf(m, __shfl_xor(m, off));
  float e0 = __expf(v0 - m);
  float e1 = (t < 36) ? __expf(v1 - m) : 0.f;
  float s = e0 + e1;
  #pragma unroll
  for (int off = 32; off > 0; off >>= 1) s += __shfl_xor(s, off);
  float inv = 1.f / s;
  e0 *= inv; e1 *= inv;

  if (outS != nullptr) {       // f-major scatter with aug rows
    outS[t * scols + i] = f2bf_bits(e0);
    if (t < 48) {
      int r2 = 64 + t;
      unsigned short bits;
      if (r2 < NF)        bits = f2bf_bits(e1);
      else if (r2 == 100) bits = 0x3F80;            // 1.0
      else if (r2 == 101) bits = f2bf_bits(bvec[i]);
      else                bits = 0;
      outS[r2 * scols + i] = bits;
    }
    return;
  }
  // T = srow @ W, row-major with aug cols
  srow[t] = e0;
  if (t < 36) srow[64 + t] = e1;
  __syncthreads();
  int c2 = 64 + t;
  int c2c = (c2 < NF) ? c2 : NF - 1;
  float a0=0.f, a1=0.f, a2=0.f, a3=0.f;
  float d0=0.f, d1=0.f, d2=0.f, d3=0.f;
  #pragma unroll 4
  for (int k = 0; k < NF; k += 4) {
    float s0 = srow[k], s1 = srow[k+1], s2 = srow[k+2], s3 = srow[k+3];
    a0 = fmaf(s0, W[(k  )*NF + t], a0);
    a1 = fmaf(s1, W[(k+1)*NF + t], a1);
    a2 = fmaf(s2, W[(k+2)*NF + t], a2);
    a3 = fmaf(s3, W[(k+3)*NF + t], a3);
    d0 = fmaf(s0, W[(k  )*NF + c2c], d0);
    d1 = fmaf(s1, W[(k+1)*NF + c2c], d1);
    d2 = fmaf(s2, W[(k+2)*NF + c2c], d2);
    d3 = fmaf(s3, W[(k+3)*NF + c2c], d3);
  }
  outT[i * NFT + t] = f2bf_bits((a0 + a1) + (a2 + a3));
  if (t < 48) {
    unsigned short bits;
    if (c2 < NF)        bits = f2bf_bits((d0 + d1) + (d2 + d3));
    else if (c2 == 100) bits = 0x3F80;
    else if (c2 == 101) bits = f2bf_bits(bvec[i]);
    else                bits = 0;
    outT[i * NFT + c2] = bits;
  }
}

// ============ unified stream GEMM: P = X[M x K](f32) @ W^T rows ([112][K] bf16) ============
// 128 thr = 2 waves x 16 rows; software-pipelined (even/odd, depth 1); xx = ||X-chunk||^2.
// MODE 0 (G/R): fused epilogue -> bucket atomics {xx, <T,P(:,<100)>, P(:,100).b, sum P(:,101)}
// MODE 1 (A):   store P^T k-slices [gridDim.y][112][M] f32.
template <int MODE>
__global__ __launch_bounds__(128, 3) void stream_kernel(
    const float* __restrict__ X, int K,
    const unsigned short* __restrict__ WT,
    const unsigned short* __restrict__ Ta,   // MODE0: [M][112] bf16
    const float* __restrict__ bI,            // MODE0: per-row bias (f32 [M])
    float* __restrict__ bk,                  // MODE0: 4 x 64 buckets
    float* __restrict__ outT5,               // MODE1: slices
    int nsteps, int Mrows) {
  int t = threadIdx.x;
  int w = t >> 6, lane = t & 63;
  int lr = lane & 15, lg = lane >> 4;
  int g0 = blockIdx.x * 32 + w * 16;
  int kbase = blockIdx.y * nsteps * 32;

  const float* pa = X + (long)(g0 + lr) * K + kbase + lg * 8;
  const unsigned short* pb = WT + (long)lr * K + kbase + lg * 8;

  f32x4 zero = {0.f, 0.f, 0.f, 0.f};
  f32x4 acc[7] = {zero, zero, zero, zero, zero, zero, zero};
  float xx = 0.f;
  bf16x8 be[7], bo[7];

  f32x4 a0e = *reinterpret_cast<const f32x4*>(pa);
  f32x4 a1e = *reinterpret_cast<const f32x4*>(pa + 4);
  #pragma unroll
  for (int ni = 0; ni < 7; ++ni)
    be[ni] = *reinterpret_cast<const bf16x8*>(pb + (long)ni * 16 * K);

  #pragma unroll 1
  for (int ks = 0; ks + 1 < nsteps; ks += 2) {
    // prefetch odd step
    f32x4 a0o = *reinterpret_cast<const f32x4*>(pa + (ks + 1) * 32);
    f32x4 a1o = *reinterpret_cast<const f32x4*>(pa + (ks + 1) * 32 + 4);
    #pragma unroll
    for (int ni = 0; ni < 7; ++ni)
      bo[ni] = *reinterpret_cast<const bf16x8*>(pb + (long)ni * 16 * K + (ks + 1) * 32);
    // compute even
    {
      #pragma unroll
      for (int j = 0; j < 4; ++j) { xx = fmaf(a0e[j], a0e[j], xx); xx = fmaf(a1e[j], a1e[j], xx); }
      bf16x8 a = cvt8(a0e, a1e);
      #pragma unroll
      for (int ni = 0; ni < 7; ++ni)
        acc[ni] = __builtin_amdgcn_mfma_f32_16x16x32_bf16(a, be[ni], acc[ni], 0, 0, 0);
    }
    // prefetch next even
    if (ks + 2 < nsteps) {
      a0e = *reinterpret_cast<const f32x4*>(pa + (ks + 2) * 32);
      a1e = *reinterpret_cast<const f32x4*>(pa + (ks + 2) * 32 + 4);
      #pragma unroll
      for (int ni = 0; ni < 7; ++ni)
        be[ni] = *reinterpret_cast<const bf16x8*>(pb + (long)ni * 16 * K + (ks + 2) * 32);
    }
    // compute odd
    {
      #pragma unroll
      for (int j = 0; j < 4; ++j) { xx = fmaf(a0o[j], a0o[j], xx); xx = fmaf(a1o[j], a1o[j], xx); }
      bf16x8 a = cvt8(a0o, a1o);
      #pragma unroll
      for (int ni = 0; ni < 7; ++ni)
        acc[ni] = __builtin_amdgcn_mfma_f32_16x16x32_bf16(a, bo[ni], acc[ni], 0, 0, 0);
    }
  }
  if (nsteps & 1) {   // last (even-index) step
    #pragma unroll
    for (int j = 0; j < 4; ++j) { xx = fmaf(a0e[j], a0e[j], xx); xx = fmaf(a1e[j], a1e[j], xx); }
    bf16x8 a = cvt8(a0e, a1e);
    #pragma unroll
    for (int ni = 0; ni < 7; ++ni)
      acc[ni] = __builtin_amdgcn_mfma_f32_16x16x32_bf16(a, be[ni], acc[ni], 0, 0, 0);
  }

  if (MODE == 1) {
    float* slice = outT5 + (long)blockIdx.y * ((long)NFT * Mrows);
    #pragma unroll
    for (int ni = 0; ni < 7; ++ni)
      *reinterpret_cast<f32x4*>(slice + (long)(ni * 16 + lr) * Mrows + g0 + lg * 4) = acc[ni];
    return;
  }

  // MODE 0 epilogue: acc[ni][j] = P[row g0+lg*4+j][col ni*16+lr]
  float s_dot = 0.f, s_rb = 0.f, s_xbg = 0.f;
  #pragma unroll
  for (int ni = 0; ni < 7; ++ni) {
    int c = ni * 16 + lr;
    if (c < NF) {
      #pragma unroll
      for (int j = 0; j < 4; ++j)
        s_dot = fmaf(acc[ni][j], bf2f(Ta[(long)(g0 + lg * 4 + j) * NFT + c]), s_dot);
    } else if (c == 100) {
      #pragma unroll
      for (int j = 0; j < 4; ++j)
        s_rb = fmaf(acc[ni][j], bI[g0 + lg * 4 + j], s_rb);
    } else if (c == 101) {
      #pragma unroll
      for (int j = 0; j < 4; ++j) s_xbg += acc[ni][j];
    }
  }
  #pragma unroll
  for (int off = 32; off > 0; off >>= 1) {
    xx    += __shfl_xor(xx, off);
    s_dot += __shfl_xor(s_dot, off);
    s_rb  += __shfl_xor(s_rb, off);
    s_xbg += __shfl_xor(s_xbg, off);
  }
  __shared__ float wred[2][4];
  if (lane == 0) { wred[w][0] = xx; wred[w][1] = s_dot; wred[w][2] = s_rb; wred[w][3] = s_xbg; }
  __syncthreads();
  if (t == 0) {
    int idx = (blockIdx.x * gridDim.y + blockIdx.y) & 63;
    atomicAdd(&bk[0 * 64 + idx], wred[0][0] + wred[1][0]);
    atomicAdd(&bk[1 * 64 + idx], wred[0][1] + wred[1][1]);
    atomicAdd(&bk[2 * 64 + idx], wred[0][2] + wred[1][2]);
    atomicAdd(&bk[3 * 64 + idx], wred[0][3] + wred[1][3]);
  }
}

// ============ Gram (f-major input YT [112][K] bf16): G += YT YT^T ============
// block 256 = 4 waves; wave w owns tile-rows {2w, 2w+1}; split-K via grid.x, atomics.
__global__ __launch_bounds__(256) void gramF_kernel(
    const unsigned short* __restrict__ YT, int K, int nsteps,
    float* __restrict__ Gout) {
  int t = threadIdx.x, w = t >> 6, lane = t & 63;
  int lr = lane & 15, lg = lane >> 4;
  int kbase = blockIdx.x * nsteps * 32;
  int ta0 = 2 * w;
  int ta1 = (ta0 + 1 < 7) ? ta0 + 1 : 6;
  f32x4 zero = {0.f, 0.f, 0.f, 0.f};
  f32x4 acc[2][7];
  #pragma unroll
  for (int q = 0; q < 2; ++q)
    #pragma unroll
    for (int tb = 0; tb < 7; ++tb) acc[q][tb] = zero;

  for (int s = 0; s < nsteps; ++s) {
    int k0 = kbase + s * 32;
    bf16x8 fa0 = *reinterpret_cast<const bf16x8*>(YT + (long)(ta0 * 16 + lr) * K + k0 + lg * 8);
    bf16x8 fa1 = *reinterpret_cast<const bf16x8*>(YT + (long)(ta1 * 16 + lr) * K + k0 + lg * 8);
    bf16x8 fb[7];
    #pragma unroll
    for (int tb = 0; tb < 7; ++tb)
      fb[tb] = *reinterpret_cast<const bf16x8*>(YT + (long)(tb * 16 + lr) * K + k0 + lg * 8);
    #pragma unroll
    for (int tb = 0; tb < 7; ++tb) {
      acc[0][tb] = __builtin_amdgcn_mfma_f32_16x16x32_bf16(fa0, fb[tb], acc[0][tb], 0, 0, 0);
      acc[1][tb] = __builtin_amdgcn_mfma_f32_16x16x32_bf16(fa1, fb[tb], acc[1][tb], 0, 0, 0);
    }
  }
  #pragma unroll
  for (int q = 0; q < 2; ++q) {
    int ta = ta0 + q;
    if (ta < 7) {
      #pragma unroll
      for (int tb = 0; tb < 7; ++tb)
        #pragma unroll
        for (int j = 0; j < 4; ++j)
          atomicAdd(Gout + (ta * 16 + lg * 4 + j) * NFT + tb * 16 + lr, acc[q][tb][j]);
    }
  }
}

// ============ Gram (row-major input Y [K][112] bf16): G += Y^T Y ============
__global__ __launch_bounds__(256) void gramR_kernel(
    const unsigned short* __restrict__ Y, int nsteps,
    float* __restrict__ Gout) {
  int t = threadIdx.x, w = t >> 6, lane = t & 63;
  int lr = lane & 15, lg = lane >> 4;
  int kbase = blockIdx.x * nsteps * 32;
  int ta0 = 2 * w;
  int ta1 = (ta0 + 1 < 7) ? ta0 + 1 : 6;
  f32x4 zero = {0.f, 0.f, 0.f, 0.f};
  f32x4 acc[2][7];
  #pragma unroll
  for (int q = 0; q < 2; ++q)
    #pragma unroll
    for (int tb = 0; tb < 7; ++tb) acc[q][tb] = zero;

  for (int s = 0; s < nsteps; ++s) {
    int k0 = kbase + s * 32;
    bf16x8 fa0, fa1, fb[7];
    #pragma unroll
    for (int e = 0; e < 8; ++e) {
      long rowoff = (long)(k0 + lg * 8 + e) * NFT;
      fa0[e] = __builtin_bit_cast(__bf16, Y[rowoff + ta0 * 16 + lr]);
      fa1[e] = __builtin_bit_cast(__bf16, Y[rowoff + ta1 * 16 + lr]);
      #pragma unroll
      for (int tb = 0; tb < 7; ++tb)
        fb[tb][e] = __builtin_bit_cast(__bf16, Y[rowoff + tb * 16 + lr]);
    }
    #pragma unroll
    for (int tb = 0; tb < 7; ++tb) {
      acc[0][tb] = __builtin_amdgcn_mfma_f32_16x16x32_bf16(fa0, fb[tb], acc[0][tb], 0, 0, 0);
      acc[1][tb] = __builtin_amdgcn_mfma_f32_16x16x32_bf16(fa1, fb[tb], acc[1][tb], 0, 0, 0);
    }
  }
  #pragma unroll
  for (int q = 0; q < 2; ++q) {
    int ta = ta0 + q;
    if (ta < 7) {
      #pragma unroll
      for (int tb = 0; tb < 7; ++tb)
        #pragma unroll
        for (int j = 0; j < 4; ++j)
          atomicAdd(Gout + (ta * 16 + lg * 4 + j) * NFT + tb * 16 + lr, acc[q][tb][j]);
    }
  }
}

// ============ loss4 pieces: <Sg,ASr> and ||ASr||^2 over f<100, slices summed ============
__global__ void l4red_kernel(const unsigned short* __restrict__ SgT,
                             const float* __restrict__ ASrT5,
                             float* __restrict__ accv) {
  int f = blockIdx.x;          // 0..99
  int t = threadIdx.x;         // 256
  float d = 0.f, n2 = 0.f;
  for (int c4 = t * 4; c4 < NG; c4 += 256 * 4) {
    f32x4 av = {0.f, 0.f, 0.f, 0.f};
    #pragma unroll
    for (int s = 0; s < 5; ++s)
      av += *reinterpret_cast<const f32x4*>(ASrT5 + (long)s * (NFT * NG) + (long)f * NG + c4);
    us4 sgb = *reinterpret_cast<const us4*>(SgT + (long)f * NG + c4);
    #pragma unroll
    for (int j = 0; j < 4; ++j) {
      float sg = bf2f(sgb[j]);
      d = fmaf(sg, av[j], d);
      n2 = fmaf(av[j], av[j], n2);
    }
  }
  #pragma unroll
  for (int off = 32; off > 0; off >>= 1) { d += __shfl_xor(d, off); n2 += __shfl_xor(n2, off); }
  __shared__ float r2[2][4];
  int lane = t & 63, w = t >> 6;
  if (lane == 0) { r2[0][w] = d; r2[1][w] = n2; }
  __syncthreads();
  if (t == 0) {
    atomicAdd(&accv[5], r2[0][0] + r2[0][1] + r2[0][2] + r2[0][3]);
    atomicAdd(&accv[7], r2[1][0] + r2[1][1] + r2[1][2] + r2[1][3]);
  }
}

// ============ finalize ============
__global__ __launch_bounds__(256) void fin_kernel(
    const float* __restrict__ accv,
    const float* __restrict__ bk1, const float* __restrict__ bk2,
    const float* __restrict__ GT1, const float* __restrict__ GT2,
    const float* __restrict__ GSg, const float* __restrict__ GSr,
    const float* __restrict__ alpha,
    float* __restrict__ out) {
  int t = threadIdx.x;
  float S1 = 0.f, S2 = 0.f, c1a = 0.f, c1b = 0.f, c2a = 0.f, c2b = 0.f, trSg = 0.f;
  for (int p = t; p < NF * NF; p += 256) {
    int f1 = p / NF, f2 = p - f1 * NF;
    S1 = fmaf(GT1[f1 * NFT + f2], GSg[f1 * NFT + f2], S1);
    S2 = fmaf(GT2[f1 * NFT + f2], GSr[f1 * NFT + f2], S2);
  }
  if (t < NF) {
    c1a = GT1[t * NFT + 100] * GSg[t * NFT + 101];
    c1b = GT1[t * NFT + 101] * GSg[t * NFT + 100];
    c2a = GT2[t * NFT + 100] * GSr[t * NFT + 101];
    c2b = GT2[t * NFT + 101] * GSr[t * NFT + 100];
    trSg = GSg[t * NFT + t];
  }
  #pragma unroll
  for (int off = 32; off > 0; off >>= 1) {
    S1 += __shfl_xor(S1, off);   S2 += __shfl_xor(S2, off);
    c1a += __shfl_xor(c1a, off); c1b += __shfl_xor(c1b, off);
    c2a += __shfl_xor(c2a, off); c2b += __shfl_xor(c2b, off);
    trSg += __shfl_xor(trSg, off);
  }
  __shared__ float red[7][4];
  __shared__ float bsum[8];
  int lane = t & 63, w = t >> 6;
  if (lane == 0) {
    red[0][w] = S1; red[1][w] = S2; red[2][w] = c1a; red[3][w] = c1b;
    red[4][w] = c2a; red[5][w] = c2b; red[6][w] = trSg;
  }
  if (t < 8) {   // bucket sums: q<4 -> stream1, q>=4 -> stream2
    float s = 0.f;
    const float* src = (t < 4) ? (bk1 + t * 64) : (bk2 + (t - 4) * 64);
    for (int i = 0; i < 64; ++i) s += src[i];
    bsum[t] = s;
  }
  __syncthreads();
  if (t == 0) {
    float S1t = red[0][0] + red[0][1] + red[0][2] + red[0][3];
    float S2t = red[1][0] + red[1][1] + red[1][2] + red[1][3];
    float C1a = red[2][0] + red[2][1] + red[2][2] + red[2][3];
    float C1b = red[3][0] + red[3][1] + red[3][2] + red[3][3];
    float C2a = red[4][0] + red[4][1] + red[4][2] + red[4][3];
    float C2b = red[5][0] + red[5][1] + red[5][2] + red[5][3];
    float trS = red[6][0] + red[6][1] + red[6][2] + red[6][3];

    // ||M||^2 terms from augmented Grams (rows/cols: 100 = ones, 101 = bias)
    float m1 = S1t + (float)NC * GSg[101 * NFT + 101] + (float)NG * GT1[101 * NFT + 101]
             + 2.f * (C1a + C1b) + 2.f * GSg[100 * NFT + 101] * GT1[100 * NFT + 101];
    float m2 = S2t + (float)NC * GSr[101 * NFT + 101] + (float)NR * GT2[101 * NFT + 101]
             + 2.f * (C2a + C2b) + 2.f * GSr[100 * NFT + 101] * GT2[100 * NFT + 101];

    float num1 = bsum[0] - 2.f * (bsum[1] + bsum[2] + bsum[3]) + m1;
    float num2 = bsum[4] - 2.f * (bsum[5] + bsum[6] + bsum[7]) + m2;
    float loss1 = num1 / ((float)NC * (float)NG);
    float loss2 = num2 / ((float)NC * (float)NR);
    float loss3 = -accv[2] / (sqrtf(accv[3]) * sqrtf(accv[4]));
    float loss4 = -accv[5] / (sqrtf(trS) * sqrtf(accv[7]));
    float l1 = alpha[0] * loss1, l2 = alpha[1] * loss2;
    float l3 = alpha[2] * loss3, l4 = alpha[3] * loss4;
    out[0] = l1 + l2 + l3 + l4;
    out[1] = l1; out[2] = l2; out[3] = l3; out[4] = l4;
  }
}

// ws layout (bytes):
//   0        : accv f32[32]                 (128)
//   128      : bk1 f32[4][64]               (1024)   {xx, dotT, rowb, xbg} for G
//   1152     : bk2 f32[4][64]               (1024)   same for R
//   2176     : GT1 f32[112][112]            (50176)
//   52352    : GT2                          (50176)
//   102528   : GSg                          (50176)
//   152704   : GSr                          (50176)  -> memset 0..202880
//   204800   : ASrT5 f32[5][112][8000]      (17,920,000)
//   18124800 : SgT  bf16[112][8000]         (1,792,000)
//   19916800 : SrT  bf16[112][20000]        (4,480,000)
//   24396800 : T1a  bf16[8000][112]         (1,792,000)
//   26188800 : T2a  bf16[8000][112]         (1,792,000)  -> 27,980,800 total

extern "C" void kernel_launch(void* const* d_in, const int* in_sizes, int n_in,
                              void* d_out, int out_size, void* d_ws, size_t ws_size,
                              hipStream_t stream) {
  const float* G  = (const float*)d_in[0];
  const float* R  = (const float*)d_in[1];
  const float* A  = (const float*)d_in[2];
  const float* C1 = (const float*)d_in[3];
  const float* C2 = (const float*)d_in[4];
  const float* Cg = (const float*)d_in[5];
  const float* Cr = (const float*)d_in[6];
  const float* Ag = (const float*)d_in[7];
  const float* Ar = (const float*)d_in[8];
  const float* bg = (const float*)d_in[9];
  const float* br = (const float*)d_in[10];
  const float* b1 = (const float*)d_in[11];
  const float* b2 = (const float*)d_in[12];
  const float* alpha = (const float*)d_in[13];

  char* ws = (char*)d_ws;
  float* accv         = (float*)(ws + 0);
  float* bk1          = (float*)(ws + 128);
  float* bk2          = (float*)(ws + 1152);
  float* GT1          = (float*)(ws + 2176);
  float* GT2          = (float*)(ws + 52352);
  float* GSg          = (float*)(ws + 102528);
  float* GSr          = (float*)(ws + 152704);
  float* ASrT5        = (float*)(ws + 204800);
  unsigned short* SgT = (unsigned short*)(ws + 18124800);
  unsigned short* SrT = (unsigned short*)(ws + 19916800);
  unsigned short* T1a = (unsigned short*)(ws + 24396800);
  unsigned short* T2a = (unsigned short*)(ws + 26188800);

  hipMemsetAsync(d_ws, 0, 202880, stream);   // accv + buckets + Grams

  pre_kernel<<<44001, 64, 0, stream>>>(C1, C2, Cg, Cr, Ag, Ar,
                                       b1, b2, bg, br, T1a, T2a, SgT, SrT, accv);

  // augmented Grams (tiny, split-K 25)
  gramF_kernel<<<25, 256, 0, stream>>>(SgT, NG, 10, GSg);
  gramF_kernel<<<25, 256, 0, stream>>>(SrT, NR, 25, GSr);
  gramR_kernel<<<25, 256, 0, stream>>>(T1a, 10, GT1);
  gramR_kernel<<<25, 256, 0, stream>>>(T2a, 10, GT2);

  // big streams: G (K=8000, 10 slices x 25 steps), R (K=20000, 5 x 125), A (MODE1)
  stream_kernel<0><<<dim3(250, 10), 128, 0, stream>>>(G, NG, SgT, T1a, b1, bk1,
                                                      (float*)nullptr, 25, NC);
  stream_kernel<0><<<dim3(250, 5), 128, 0, stream>>>(R, NR, SrT, T2a, b2, bk2,
                                                     (float*)nullptr, 125, NC);
  stream_kernel<1><<<dim3(250, 5), 128, 0, stream>>>(A, NR, SrT,
                                                     (const unsigned short*)nullptr,
                                                     (const float*)nullptr, (float*)nullptr,
                                                     ASrT5, 125, NG);

  l4red_kernel<<<NF, 256, 0, stream>>>(SgT, ASrT5, accv);
  fin_kernel<<<1, 256, 0, stream>>>(accv, bk1, bk2, GT1, GT2, GSg, GSr,
                                    alpha, (float*)d_out);
}

// Round 7
// 671.778 us; speedup vs baseline: 1.5708x; 1.5708x over previous
//
#include <hip/hip_runtime.h>

typedef __bf16 bf16x8 __attribute__((ext_vector_type(8)));
typedef float  f32x4  __attribute__((ext_vector_type(4)));
typedef unsigned short us4 __attribute__((ext_vector_type(4)));

#define N_CELLS 8000
#define N_GENES 8000
#define N_REG   20000
#define NF      100
#define KP      128     // padded K (factors) for MFMA
#define NFT     112     // padded factor count for ASr output (7*16)
#define KSPLIT  5       // split-K slices for ASr

static __device__ __forceinline__ unsigned short f2bf_bits(float f) {
  unsigned u = __builtin_bit_cast(unsigned, f);
  u = (u + 0x7FFFu + ((u >> 16) & 1u)) >> 16;   // RNE
  return (unsigned short)u;
}
static __device__ __forceinline__ __bf16 f2bf(float f) {
  unsigned short h = f2bf_bits(f);
  return __builtin_bit_cast(__bf16, h);
}
static __device__ __forceinline__ float bf2f(unsigned short s) {
  unsigned u = ((unsigned)s) << 16;
  return __builtin_bit_cast(float, u);
}
static __device__ __forceinline__ bf16x8 cvt8(f32x4 v0, f32x4 v1) {
  bf16x8 r;
  r[0]=f2bf(v0[0]); r[1]=f2bf(v0[1]); r[2]=f2bf(v0[2]); r[3]=f2bf(v0[3]);
  r[4]=f2bf(v1[0]); r[5]=f2bf(v1[1]); r[6]=f2bf(v1[2]); r[7]=f2bf(v1[3]);
  return r;
}

// ---------------- fused pre-pass: all 4 softmaxes (+matvec for T1/T2) + loss3.
// (verbatim round-5 version; 725 µs baseline)
__global__ __launch_bounds__(64) void pre_kernel(
    const float* __restrict__ C1, const float* __restrict__ C2,
    const float* __restrict__ Cg, const float* __restrict__ Cr,
    const float* __restrict__ Ag, const float* __restrict__ Ar,
    unsigned short* __restrict__ T1, unsigned short* __restrict__ T2,
    unsigned short* __restrict__ Sg, unsigned short* __restrict__ Sr,
    unsigned short* __restrict__ SrT,
    float* __restrict__ accv) {
  __shared__ float srow[NF];
  int b = blockIdx.x, t = threadIdx.x;
  if (b >= 44000) {            // loss3
    float d = 0.f, na = 0.f, nr = 0.f;
    for (int i = t; i < NF * NF; i += 64) {
      float a = Ag[i], r = Ar[i];
      d = fmaf(a, r, d); na = fmaf(a, a, na); nr = fmaf(r, r, nr);
    }
    #pragma unroll
    for (int off = 32; off > 0; off >>= 1) {
      d += __shfl_xor(d, off); na += __shfl_xor(na, off); nr += __shfl_xor(nr, off);
    }
    if (t == 0) { accv[2] = d; accv[3] = na; accv[4] = nr; }
    return;
  }
  const float* C; const float* W = nullptr;
  unsigned short* outR = nullptr; unsigned short* outT = nullptr;
  bool isSr = false;
  int i;
  if (b < 8000)       { C = C1; W = Ag; outT = T1; i = b; }
  else if (b < 16000) { C = C2; W = Ar; outT = T2; i = b - 8000; }
  else if (b < 24000) { C = Cg; outR = Sg; i = b - 16000; }
  else                { C = Cr; outR = Sr; isSr = true; i = b - 24000; }

  float v0 = C[i * NF + t];
  float v1 = (t < 36) ? C[i * NF + 64 + t] : -3.0e38f;
  float m = fmaxf(v0, v1);
  #pragma unroll
  for (int off = 32; off > 0; off >>= 1) m = fmaxf(m, __shfl_xor(m, off));
  float e0 = __expf(v0 - m);
  float e1 = (t < 36) ? __expf(v1 - m) : 0.f;
  float s = e0 + e1;
  #pragma unroll
  for (int off = 32; off > 0; off >>= 1) s += __shfl_xor(s, off);
  float inv = 1.f / s;
  e0 *= inv; e1 *= inv;

  if (outT == nullptr) {
    unsigned short b0 = f2bf_bits(e0);
    unsigned short b1 = (t < 36) ? f2bf_bits(e1) : (unsigned short)0;
    outR[i * KP + t] = b0;
    outR[i * KP + 64 + t] = b1;
    if (isSr) {
      SrT[t * N_REG + i] = b0;
      if (t < 48) SrT[(64 + t) * N_REG + i] = b1;
    }
    return;
  }
  srow[t] = e0;
  if (t < 36) srow[64 + t] = e1;
  __syncthreads();
  int c2 = 64 + t;
  int c2c = (c2 < NF) ? c2 : NF - 1;
  float a0=0.f, a1=0.f, a2=0.f, a3=0.f;
  float d0=0.f, d1=0.f, d2=0.f, d3=0.f;
  #pragma unroll 4
  for (int k = 0; k < NF; k += 4) {
    float s0 = srow[k], s1 = srow[k+1], s2 = srow[k+2], s3 = srow[k+3];
    a0 = fmaf(s0, W[(k  )*NF + t], a0);
    a1 = fmaf(s1, W[(k+1)*NF + t], a1);
    a2 = fmaf(s2, W[(k+2)*NF + t], a2);
    a3 = fmaf(s3, W[(k+3)*NF + t], a3);
    d0 = fmaf(s0, W[(k  )*NF + c2c], d0);
    d1 = fmaf(s1, W[(k+1)*NF + c2c], d1);
    d2 = fmaf(s2, W[(k+2)*NF + c2c], d2);
    d3 = fmaf(s3, W[(k+3)*NF + c2c], d3);
  }
  outT[i * KP + t]  = f2bf_bits((a0 + a1) + (a2 + a3));
  outT[i * KP + c2] = (c2 < NF) ? f2bf_bits((d0 + d1) + (d2 + d3)) : (unsigned short)0;
}

// ---------------- fused residual SSE (verbatim round-5; proven good)
__global__ __launch_bounds__(256, 3) void resid_kernel(
    const float* __restrict__ X,
    const unsigned short* __restrict__ Tm,
    const unsigned short* __restrict__ Sm,
    const float* __restrict__ bcol,
    const float* __restrict__ brow,
    int N, float* __restrict__ buckets) {
  __shared__ char ldsbuf[49152];
  char* ldsT = ldsbuf;
  char* ldsS = ldsbuf + 16384;
  int t = threadIdx.x;
  int wid = t >> 6, lane = t & 63;
  int lr = lane & 15, lg = lane >> 4;
  long r0blk = (long)blockIdx.y * 64;
  long c0blk = (long)blockIdx.x * 128;
  int r0 = (wid >> 1) * 32;
  int c0 = (wid & 1) * 64;

  bf16x8 sT[4], sS[8];
  #pragma unroll
  for (int i2 = 0; i2 < 4; ++i2) {
    int g = i2 * 256 + t, row = g >> 4, gi = g & 15;
    sT[i2] = *reinterpret_cast<const bf16x8*>(Tm + (r0blk + row) * KP + gi * 8);
  }
  #pragma unroll
  for (int i2 = 0; i2 < 8; ++i2) {
    int g = i2 * 256 + t, row = g >> 4, gi = g & 15;
    sS[i2] = *reinterpret_cast<const bf16x8*>(Sm + (c0blk + row) * KP + gi * 8);
  }

  f32x4 xv[2][4];
  #pragma unroll
  for (int ri = 0; ri < 2; ++ri) {
    long row = r0blk + r0 + ri * 16 + lr;
    #pragma unroll
    for (int ci = 0; ci < 4; ++ci) {
      long cb = c0blk + c0 + ci * 16 + lg * 4;
      if (cb < N) xv[ri][ci] = *reinterpret_cast<const f32x4*>(X + row * N + cb);
      else        xv[ri][ci] = f32x4{0.f, 0.f, 0.f, 0.f};
    }
  }

  #pragma unroll
  for (int i2 = 0; i2 < 4; ++i2) {
    int g = i2 * 256 + t, row = g >> 4, gi = g & 15;
    int off = row * 256 + ((gi * 16) ^ ((row & 7) << 4));
    *reinterpret_cast<bf16x8*>(ldsT + off) = sT[i2];
  }
  #pragma unroll
  for (int i2 = 0; i2 < 8; ++i2) {
    int g = i2 * 256 + t, row = g >> 4, gi = g & 15;
    int off = row * 256 + ((gi * 16) ^ ((row & 7) << 4));
    *reinterpret_cast<bf16x8*>(ldsS + off) = sS[i2];
  }
  __syncthreads();

  f32x4 zero = {0.f, 0.f, 0.f, 0.f};
  f32x4 acc[4][2] = {{zero, zero}, {zero, zero}, {zero, zero}, {zero, zero}};
  #pragma unroll
  for (int ks = 0; ks < 4; ++ks) {
    bf16x8 a[4], bfr[2];
    #pragma unroll
    for (int ci = 0; ci < 4; ++ci) {
      int row = c0 + ci * 16 + lr;
      int off = row * 256 + (((ks * 64) + (lg * 16)) ^ ((row & 7) << 4));
      a[ci] = *reinterpret_cast<const bf16x8*>(ldsS + off);
    }
    #pragma unroll
    for (int ri = 0; ri < 2; ++ri) {
      int row = r0 + ri * 16 + lr;
      int off = row * 256 + (((ks * 64) + (lg * 16)) ^ ((row & 7) << 4));
      bfr[ri] = *reinterpret_cast<const bf16x8*>(ldsT + off);
    }
    #pragma unroll
    for (int ci = 0; ci < 4; ++ci)
      #pragma unroll
      for (int ri = 0; ri < 2; ++ri)
        acc[ci][ri] = __builtin_amdgcn_mfma_f32_16x16x32_bf16(a[ci], bfr[ri], acc[ci][ri], 0, 0, 0);
  }

  float brv[2];
  #pragma unroll
  for (int ri = 0; ri < 2; ++ri) brv[ri] = brow[r0blk + r0 + ri * 16 + lr];

  float sse = 0.f;
  #pragma unroll
  for (int ci = 0; ci < 4; ++ci) {
    long cb = c0blk + c0 + ci * 16 + lg * 4;
    if (cb < N) {
      f32x4 bc = *reinterpret_cast<const f32x4*>(bcol + cb);
      #pragma unroll
      for (int ri = 0; ri < 2; ++ri) {
        f32x4 x = xv[ri][ci];
        #pragma unroll
        for (int j = 0; j < 4; ++j) {
          float e = x[j] - acc[ci][ri][j] - bc[j] - brv[ri];
          sse = fmaf(e, e, sse);
        }
      }
    }
  }
  #pragma unroll
  for (int off = 32; off > 0; off >>= 1) sse += __shfl_xor(sse, off);
  __shared__ float wsum[4];
  if (lane == 0) wsum[wid] = sse;
  __syncthreads();
  if (t == 0)
    atomicAdd(&buckets[(blockIdx.y * gridDim.x + blockIdx.x) & 63],
              wsum[0] + wsum[1] + wsum[2] + wsum[3]);
}

// ---------------- ASr = A @ Sr — NEW: LDS-staged A with coalesced reads.
// Block: 256 thr = 4 waves; 64 genes x 112 factors; k-chunk 4000 (y=5 slices).
// Stage [64 genes][128 k] bf16 (16 KB, XOR swizzle (row&7)<<4) per iter;
// 31 iters of 128k + 1 tail iter of 32k = 4000. Global reads: 512 B runs/row.
// SrT b-frags read from global (4.5 MB, L2-resident).
__global__ __launch_bounds__(256) void asr_kernel(
    const float* __restrict__ A,
    const unsigned short* __restrict__ SrT,
    float* __restrict__ ASr5) {
  __shared__ char lds[16384];
  int t = threadIdx.x;
  int w = t >> 6, lane = t & 63;
  int lr = lane & 15, lg = lane >> 4;
  int gBase = blockIdx.x * 64;
  int kb0 = blockIdx.y * (N_REG / KSPLIT);   // 4000

  f32x4 zero = {0.f, 0.f, 0.f, 0.f};
  f32x4 acc[7] = {zero, zero, zero, zero, zero, zero, zero};

  const unsigned short* pb = SrT + (long)lr * N_REG + lg * 8;

  #pragma unroll 1
  for (int it = 0; it < 32; ++it) {
    int kb = kb0 + it * 128;
    __syncthreads();
    if (it < 31) {
      #pragma unroll
      for (int p = 0; p < 4; ++p) {
        int flat = p * 2048 + t * 8;
        int row = flat >> 7, kk = flat & 127;
        const float* src = A + (long)(gBase + row) * N_REG + kb + kk;
        f32x4 v0 = *reinterpret_cast<const f32x4*>(src);
        f32x4 v1 = *reinterpret_cast<const f32x4*>(src + 4);
        int off = row * 256 + ((kk * 2) ^ ((row & 7) << 4));
        *reinterpret_cast<bf16x8*>(lds + off) = cvt8(v0, v1);
      }
    } else {
      int row = t >> 2, kk = (t & 3) * 8;
      const float* src = A + (long)(gBase + row) * N_REG + kb + kk;
      f32x4 v0 = *reinterpret_cast<const f32x4*>(src);
      f32x4 v1 = *reinterpret_cast<const f32x4*>(src + 4);
      int off = row * 256 + ((kk * 2) ^ ((row & 7) << 4));
      *reinterpret_cast<bf16x8*>(lds + off) = cvt8(v0, v1);
    }
    __syncthreads();
    int nk = (it < 31) ? 4 : 1;
    #pragma unroll 1
    for (int ks = 0; ks < nk; ++ks) {
      int row = w * 16 + lr;
      int off = row * 256 + (((ks * 64) + lg * 16) ^ ((row & 7) << 4));
      bf16x8 ag = *reinterpret_cast<const bf16x8*>(lds + off);
      #pragma unroll
      for (int ni = 0; ni < 7; ++ni) {
        bf16x8 b = *reinterpret_cast<const bf16x8*>(pb + (long)ni * 16 * N_REG + kb + ks * 32);
        acc[ni] = __builtin_amdgcn_mfma_f32_16x16x32_bf16(ag, b, acc[ni], 0, 0, 0);
      }
    }
  }

  // D: row(m=gene) = lg*4+j, col(n=factor) = ni*16+lr  (same mapping as r5)
  float* slice = ASr5 + (long)blockIdx.y * (N_GENES * NFT);
  int g0 = gBase + w * 16;
  #pragma unroll
  for (int ni = 0; ni < 7; ++ni) {
    int f = ni * 16 + lr;
    #pragma unroll
    for (int j = 0; j < 4; ++j)
      slice[(g0 + lg * 4 + j) * NFT + f] = acc[ni][j];
  }
}

// ---------------- loss4 pieces (verbatim round-5)
__global__ void l4red_kernel(const unsigned short* __restrict__ Sgbf,
                             const float* __restrict__ ASr5,
                             float* __restrict__ accv) {
  const int NV = N_GENES * NFT / 4;
  int t = blockIdx.x * blockDim.x + threadIdx.x;
  float d = 0.f, n1 = 0.f, n2 = 0.f;
  for (int q = t; q < NV; q += gridDim.x * blockDim.x) {
    int g = q / (NFT / 4);
    int f4 = (q - g * (NFT / 4)) * 4;
    f32x4 av = {0.f, 0.f, 0.f, 0.f};
    #pragma unroll
    for (int s = 0; s < KSPLIT; ++s)
      av += *reinterpret_cast<const f32x4*>(ASr5 + (long)s * (N_GENES * NFT) + g * NFT + f4);
    us4 sgb = *reinterpret_cast<const us4*>(Sgbf + g * KP + f4);
    #pragma unroll
    for (int j = 0; j < 4; ++j) {
      float sg = bf2f(sgb[j]);
      d = fmaf(sg, av[j], d); n1 = fmaf(sg, sg, n1); n2 = fmaf(av[j], av[j], n2);
    }
  }
  #pragma unroll
  for (int off = 32; off > 0; off >>= 1) {
    d += __shfl_xor(d, off); n1 += __shfl_xor(n1, off); n2 += __shfl_xor(n2, off);
  }
  __shared__ float r3[3][4];
  int lane = threadIdx.x & 63, w = threadIdx.x >> 6;
  if (lane == 0) { r3[0][w] = d; r3[1][w] = n1; r3[2][w] = n2; }
  __syncthreads();
  if (threadIdx.x == 0) {
    atomicAdd(&accv[5], r3[0][0] + r3[0][1] + r3[0][2] + r3[0][3]);
    atomicAdd(&accv[6], r3[1][0] + r3[1][1] + r3[1][2] + r3[1][3]);
    atomicAdd(&accv[7], r3[2][0] + r3[2][1] + r3[2][2] + r3[2][3]);
  }
}

// ---------------- finalize (verbatim round-5)
__global__ void fin_kernel(const float* __restrict__ accv,
                           const float* __restrict__ bk1,
                           const float* __restrict__ bk2,
                           const float* __restrict__ alpha,
                           float* __restrict__ out) {
  if (threadIdx.x == 0) {
    float s1 = 0.f, s2 = 0.f;
    for (int i = 0; i < 64; ++i) { s1 += bk1[i]; s2 += bk2[i]; }
    float loss1 = s1 / 64000000.0f;
    float loss2 = s2 / 160000000.0f;
    float loss3 = -accv[2] / (sqrtf(accv[3]) * sqrtf(accv[4]));
    float loss4 = -accv[5] / (sqrtf(accv[6]) * sqrtf(accv[7]));
    float l1 = alpha[0] * loss1, l2 = alpha[1] * loss2;
    float l3 = alpha[2] * loss3, l4 = alpha[3] * loss4;
    out[0] = l1 + l2 + l3 + l4;
    out[1] = l1; out[2] = l2; out[3] = l3; out[4] = l4;
  }
}

// ws layout (bytes): identical to round 5
//   0 accv[16] | 64 bk1[64] | 320 bk2[64] | 1024 ASr5 [5][8000][112] f32
//   17921024 T1 | 19969024 T2 | 22017024 Sg | 24065024 Sr | 29185024 SrT

extern "C" void kernel_launch(void* const* d_in, const int* in_sizes, int n_in,
                              void* d_out, int out_size, void* d_ws, size_t ws_size,
                              hipStream_t stream) {
  const float* G  = (const float*)d_in[0];
  const float* R  = (const float*)d_in[1];
  const float* A  = (const float*)d_in[2];
  const float* C1 = (const float*)d_in[3];
  const float* C2 = (const float*)d_in[4];
  const float* Cg = (const float*)d_in[5];
  const float* Cr = (const float*)d_in[6];
  const float* Ag = (const float*)d_in[7];
  const float* Ar = (const float*)d_in[8];
  const float* bg = (const float*)d_in[9];
  const float* br = (const float*)d_in[10];
  const float* b1 = (const float*)d_in[11];
  const float* b2 = (const float*)d_in[12];
  const float* alpha = (const float*)d_in[13];

  char* ws = (char*)d_ws;
  float* accv           = (float*)(ws + 0);
  float* buckets1       = (float*)(ws + 64);
  float* buckets2       = (float*)(ws + 320);
  float* ASr5           = (float*)(ws + 1024);
  unsigned short* T1    = (unsigned short*)(ws + 17921024);
  unsigned short* T2    = (unsigned short*)(ws + 19969024);
  unsigned short* Sg    = (unsigned short*)(ws + 22017024);
  unsigned short* Sr    = (unsigned short*)(ws + 24065024);
  unsigned short* SrT   = (unsigned short*)(ws + 29185024);

  hipMemsetAsync(d_ws, 0, 576, stream);

  pre_kernel<<<44001, 64, 0, stream>>>(C1, C2, Cg, Cr, Ag, Ar,
                                       T1, T2, Sg, Sr, SrT, accv);

  resid_kernel<<<dim3(63, 125), 256, 0, stream>>>(G, T1, Sg, bg, b1, N_GENES, buckets1);
  resid_kernel<<<dim3(157, 125), 256, 0, stream>>>(R, T2, Sr, br, b2, N_REG, buckets2);

  asr_kernel<<<dim3(125, KSPLIT), 256, 0, stream>>>(A, SrT, ASr5);

  l4red_kernel<<<128, 256, 0, stream>>>(Sg, ASr5, accv);
  fin_kernel<<<1, 64, 0, stream>>>(accv, buckets1, buckets2, alpha, (float*)d_out);
}